// Round 5
// baseline (746.569 us; speedup 1.0000x reference)
//
#include <hip/hip_runtime.h>
#include <hip/hip_bf16.h>

// Problem constants (match reference)
#define NN 100000
#define NG 512
#define H  128

typedef _Float16 half8 __attribute__((ext_vector_type(8)));
typedef _Float16 half4v __attribute__((ext_vector_type(4)));

// ---------------------------------------------------------------------------
// CSR build: histogram of dst
__global__ __launch_bounds__(256) void k_hist(const int* __restrict__ dst,
                                              int* __restrict__ deg, int E) {
    int e = blockIdx.x * 256 + threadIdx.x;
    if (e < E) atomicAdd(&deg[dst[e]], 1);
}

// per-block exclusive scan (256 elems), partial sums to bsum
__global__ __launch_bounds__(256) void k_scan_block(const int* __restrict__ deg,
                                                    int* __restrict__ rowptr,
                                                    int* __restrict__ bsum, int n) {
    __shared__ int s[256];
    int tid = threadIdx.x;
    int i = blockIdx.x * 256 + tid;
    int v = (i < n) ? deg[i] : 0;
    s[tid] = v;
    __syncthreads();
    #pragma unroll
    for (int off = 1; off < 256; off <<= 1) {
        int t = (tid >= off) ? s[tid - off] : 0;
        __syncthreads();
        s[tid] += t;
        __syncthreads();
    }
    if (i < n) rowptr[i] = s[tid] - v;            // exclusive within block
    if (tid == 255) bsum[blockIdx.x] = s[255];    // block total
}

// scan of block sums (NB <= 512), single block
__global__ __launch_bounds__(512) void k_scan_top(int* __restrict__ bsum, int nb) {
    __shared__ int s[512];
    int tid = threadIdx.x;
    int v = (tid < nb) ? bsum[tid] : 0;
    s[tid] = v;
    __syncthreads();
    #pragma unroll
    for (int off = 1; off < 512; off <<= 1) {
        int t = (tid >= off) ? s[tid - off] : 0;
        __syncthreads();
        s[tid] += t;
        __syncthreads();
    }
    if (tid < nb) bsum[tid] = s[tid] - v;         // exclusive
}

// finalize: rowptr += block offset; cursor = rowptr; dinv = rsqrt(deg+1)
__global__ __launch_bounds__(256) void k_scan_fin(int* __restrict__ rowptr,
                                                  const int* __restrict__ bsum,
                                                  const int* __restrict__ deg,
                                                  int* __restrict__ cursor,
                                                  float* __restrict__ dinv,
                                                  int n, int E) {
    int i = blockIdx.x * 256 + threadIdx.x;
    if (i >= n) return;
    int r = rowptr[i] + bsum[i >> 8];
    rowptr[i] = r;
    cursor[i] = r;
    dinv[i] = rsqrtf((float)deg[i] + 1.0f);       // +1 self-loop; always > 0
    if (i == 0) rowptr[n] = E;
}

// fill CSR column array
__global__ __launch_bounds__(256) void k_fill(const int* __restrict__ src,
                                              const int* __restrict__ dst,
                                              int* __restrict__ cursor,
                                              int* __restrict__ col, int E) {
    int e = blockIdx.x * 256 + threadIdx.x;
    if (e >= E) return;
    int d = dst[e];
    int pos = atomicAdd(&cursor[d], 1);
    col[pos] = src[e];
}

// ---------------------------------------------------------------------------
// Sort each CSR row ascending (locality only — correctness is order-free).
// One wave per node, 64-lane bitonic sort; rows with deg > 64 left unsorted
// (Poisson(16): never happens in practice).
__global__ __launch_bounds__(256) void k_sortrows(const int* __restrict__ rowptr,
                                                  int* __restrict__ col, int n) {
    int node = blockIdx.x * 4 + (threadIdx.x >> 6);
    int lane = threadIdx.x & 63;
    if (node >= n) return;
    int e0 = rowptr[node], end = rowptr[node + 1];
    int deg = end - e0;
    if (deg <= 1 || deg > 64) return;             // wave-uniform branch
    int v = (lane < deg) ? col[e0 + lane] : 0x7fffffff;
    #pragma unroll
    for (int k = 2; k <= 64; k <<= 1) {
        #pragma unroll
        for (int j = k >> 1; j > 0; j >>= 1) {
            int p = __shfl_xor(v, j);
            bool up = ((lane & k) == 0);
            bool keepmin = (((lane & j) == 0) == up);
            v = keepmin ? min(v, p) : max(v, p);
        }
    }
    if (lane < deg) col[e0 + lane] = v;
}

// ---------------------------------------------------------------------------
// C_h[n x 128] (fp16) = (A[n x 128] @ W[128 x 128]) * scale[row]; 32 rows/block.
__global__ __launch_bounds__(256) void gemm128h(const float* __restrict__ A,
                                                const float* __restrict__ W,
                                                const float* __restrict__ scale,
                                                _Float16* __restrict__ C) {
    __shared__ float xs[32][64];
    __shared__ float ws[64][128];
    const int tid = threadIdx.x;
    const int row0 = blockIdx.x * 32;
    const int tx = tid & 31;   // col group: cols 4*tx .. 4*tx+3
    const int ty = tid >> 5;   // row group: rows 4*ty .. 4*ty+3
    float acc[4][4] = {};

    for (int kc = 0; kc < 128; kc += 64) {
        #pragma unroll
        for (int i = tid; i < 32 * 16; i += 256) {
            int r = i >> 4, k4 = i & 15;
            ((float4*)xs[r])[k4] =
                ((const float4*)(A + (size_t)(row0 + r) * H + kc))[k4];
        }
        #pragma unroll
        for (int i = tid; i < 64 * 32; i += 256) {
            int k = i >> 5, c4 = i & 31;
            ((float4*)ws[k])[c4] = ((const float4*)(W + (size_t)(kc + k) * H))[c4];
        }
        __syncthreads();
        #pragma unroll
        for (int k = 0; k < 64; ++k) {
            float4 wv = ((float4*)ws[k])[tx];
            float xv[4];
            #pragma unroll
            for (int r = 0; r < 4; ++r) xv[r] = xs[4 * ty + r][k];
            #pragma unroll
            for (int r = 0; r < 4; ++r) {
                acc[r][0] += xv[r] * wv.x;
                acc[r][1] += xv[r] * wv.y;
                acc[r][2] += xv[r] * wv.z;
                acc[r][3] += xv[r] * wv.w;
            }
        }
        __syncthreads();
    }
    #pragma unroll
    for (int r = 0; r < 4; ++r) {
        int row = row0 + 4 * ty + r;
        float sc = scale[row];
        half4v v;
        v[0] = (_Float16)(acc[r][0] * sc);
        v[1] = (_Float16)(acc[r][1] * sc);
        v[2] = (_Float16)(acc[r][2] * sc);
        v[3] = (_Float16)(acc[r][3] * sc);
        ((half4v*)(C + (size_t)row * H))[tx] = v;
    }
}

// ---------------------------------------------------------------------------
// Gather core, fp16 rows (256B). One wave per node. Quarter-wave q handles
// edge slot 4g+q; lane loads 16B (8 halves) of the row => one 64-lane load
// fetches FOUR rows. col indices bulk-loaded 64 at a time, broadcast by shfl.
// Accumulation fp32. After the xor-16/32 combine all lanes hold the full sum
// for features l16*8 .. l16*8+7.
__device__ __forceinline__ void gather_rows_h(const half8* __restrict__ t8,
                                              const int* __restrict__ col,
                                              int node, int e0, int end,
                                              float acc[8]) {
    const int lane = threadIdx.x & 63;
    const int q = lane >> 4;
    const int l16 = lane & 15;
    float a0[8] = {}, a1[8] = {};
    if (q == 0) {                                   // self-loop row
        half8 v = t8[(size_t)node * 16 + l16];
        #pragma unroll
        for (int i = 0; i < 8; ++i) a0[i] = (float)v[i];
    }
    for (int base = e0; base < end; base += 64) {
        int ce = base + lane;
        int cidx = (ce < end) ? col[ce] : 0;
        int m = min(64, end - base);
        int nf = m >> 2;                            // full groups of 4 edges
        int g = 0;
        for (; g + 2 <= nf; g += 2) {
            int s0 = __shfl(cidx, 4 * g + q);
            int s1 = __shfl(cidx, 4 * g + 4 + q);
            half8 v0 = t8[(size_t)s0 * 16 + l16];
            half8 v1 = t8[(size_t)s1 * 16 + l16];
            #pragma unroll
            for (int i = 0; i < 8; ++i) {
                a0[i] += (float)v0[i];
                a1[i] += (float)v1[i];
            }
        }
        if (g < nf) {
            int s0 = __shfl(cidx, 4 * g + q);
            half8 v0 = t8[(size_t)s0 * 16 + l16];
            #pragma unroll
            for (int i = 0; i < 8; ++i) a0[i] += (float)v0[i];
        }
        int tail = m & 3;
        if (tail) {
            int s = __shfl(cidx, 4 * nf + q);       // all lanes active here
            if (q < tail) {
                half8 v = t8[(size_t)s * 16 + l16];
                #pragma unroll
                for (int i = 0; i < 8; ++i) a0[i] += (float)v[i];
            }
        }
    }
    #pragma unroll
    for (int i = 0; i < 8; ++i) {
        float t = a0[i] + a1[i];
        t += __shfl_xor(t, 16);
        t += __shfl_xor(t, 32);
        acc[i] = t;
    }
}

// gather layer 1: out[n] (fp32) = relu(dinv[n]*(tS[n] + sum in-edges) + b)
__global__ __launch_bounds__(256) void k_gather1(const _Float16* __restrict__ tS,
                                                 const int* __restrict__ rowptr,
                                                 const int* __restrict__ col,
                                                 const float* __restrict__ dinv,
                                                 const float* __restrict__ b,
                                                 float* __restrict__ out, int n) {
    int node = blockIdx.x * 4 + (threadIdx.x >> 6);
    int lane = threadIdx.x & 63;
    int q = lane >> 4, l16 = lane & 15;
    if (node >= n) return;
    int e0 = rowptr[node], end = rowptr[node + 1];
    float acc[8];
    gather_rows_h((const half8*)tS, col, node, e0, end, acc);
    if (q == 0) {
        float dn = dinv[node];
        const float4* b4 = (const float4*)b;
        float4 bb0 = b4[2 * l16], bb1 = b4[2 * l16 + 1];
        float4 r0, r1;
        r0.x = fmaxf(dn * acc[0] + bb0.x, 0.0f);
        r0.y = fmaxf(dn * acc[1] + bb0.y, 0.0f);
        r0.z = fmaxf(dn * acc[2] + bb0.z, 0.0f);
        r0.w = fmaxf(dn * acc[3] + bb0.w, 0.0f);
        r1.x = fmaxf(dn * acc[4] + bb1.x, 0.0f);
        r1.y = fmaxf(dn * acc[5] + bb1.y, 0.0f);
        r1.z = fmaxf(dn * acc[6] + bb1.z, 0.0f);
        r1.w = fmaxf(dn * acc[7] + bb1.w, 0.0f);
        float4* o = (float4*)(out + (size_t)node * H + l16 * 8);
        o[0] = r0;
        o[1] = r1;
    }
}

// gather layer 2 fused with pool head: v = relu(...); pool[batch[n]] += dot(v, Wp)
__global__ __launch_bounds__(256) void k_gather2(const _Float16* __restrict__ tS,
                                                 const int* __restrict__ rowptr,
                                                 const int* __restrict__ col,
                                                 const float* __restrict__ dinv,
                                                 const float* __restrict__ b,
                                                 const float* __restrict__ Wp,
                                                 const int* __restrict__ batch,
                                                 float* __restrict__ pool,
                                                 float* __restrict__ cnt, int n) {
    int node = blockIdx.x * 4 + (threadIdx.x >> 6);
    int lane = threadIdx.x & 63;
    int l16 = lane & 15;
    if (node >= n) return;
    int e0 = rowptr[node], end = rowptr[node + 1];
    float acc[8];
    gather_rows_h((const half8*)tS, col, node, e0, end, acc);
    float dn = dinv[node];
    const float4* b4 = (const float4*)b;
    const float4* w4 = (const float4*)Wp;
    float4 bb0 = b4[2 * l16], bb1 = b4[2 * l16 + 1];
    float4 wp0 = w4[2 * l16], wp1 = w4[2 * l16 + 1];
    float s = fmaxf(dn * acc[0] + bb0.x, 0.0f) * wp0.x +
              fmaxf(dn * acc[1] + bb0.y, 0.0f) * wp0.y +
              fmaxf(dn * acc[2] + bb0.z, 0.0f) * wp0.z +
              fmaxf(dn * acc[3] + bb0.w, 0.0f) * wp0.w +
              fmaxf(dn * acc[4] + bb1.x, 0.0f) * wp1.x +
              fmaxf(dn * acc[5] + bb1.y, 0.0f) * wp1.y +
              fmaxf(dn * acc[6] + bb1.z, 0.0f) * wp1.z +
              fmaxf(dn * acc[7] + bb1.w, 0.0f) * wp1.w;
    // all quarters hold identical partials per l16; reduce over l16
    s += __shfl_xor(s, 1);
    s += __shfl_xor(s, 2);
    s += __shfl_xor(s, 4);
    s += __shfl_xor(s, 8);
    if (lane == 0) {
        int g = batch[node];
        atomicAdd(&pool[g], s);
        atomicAdd(&cnt[g], 1.0f);
    }
}

// ---------------------------------------------------------------------------
__global__ __launch_bounds__(256) void final_out_kernel(const float* __restrict__ pool,
                                                        const float* __restrict__ cnt,
                                                        const float* __restrict__ bp,
                                                        float* __restrict__ out, int g) {
    int i = blockIdx.x * 256 + threadIdx.x;
    if (i < g) out[i] = pool[i] / fmaxf(cnt[i], 1.0f) + bp[0];
}

// ---------------------------------------------------------------------------
extern "C" void kernel_launch(void* const* d_in, const int* in_sizes, int n_in,
                              void* d_out, int out_size, void* d_ws, size_t ws_size,
                              hipStream_t stream) {
    const float* x     = (const float*)d_in[0];
    const int*   ei    = (const int*)d_in[1];   // [2, E]: src = ei[0:E], dst = ei[E:2E]
    const int*   batch = (const int*)d_in[2];
    const float* W1    = (const float*)d_in[3];
    const float* b1    = (const float*)d_in[4];
    const float* W2    = (const float*)d_in[5];
    const float* b2    = (const float*)d_in[6];
    const float* Wp    = (const float*)d_in[7];
    const float* bp    = (const float*)d_in[8];
    float* out = (float*)d_out;

    const int E = in_sizes[1] / 2;   // 1,600,000
    const int* src = ei;
    const int* dst = ei + E;

    // workspace layout (aligned chunks)
    const size_t BUFH = (size_t)NN * H * sizeof(_Float16);   // 25.6 MB (fp16 msgs)
    const size_t BUFF = (size_t)NN * H * sizeof(float);      // 51.2 MB (fp32 h1)
    const size_t NI  = 401408;                                // >= (NN+1)*4, 4KB-mult
    char* ws = (char*)d_ws;
    size_t off = 0;
    _Float16* tS  = (_Float16*)(ws + off); off += BUFH;      // GEMM outputs (fp16)
    float* h1     = (float*)(ws + off); off += BUFF;         // layer-1 activations
    int*   deg    = (int*)  (ws + off); off += NI;
    int*   rowptr = (int*)  (ws + off); off += NI;
    int*   cursor = (int*)  (ws + off); off += NI;
    float* dinv   = (float*)(ws + off); off += NI;
    int*   col    = (int*)  (ws + off); off += ((size_t)E * 4 + 4095) / 4096 * 4096;
    int*   bsum   = (int*)  (ws + off); off += 4096;
    float* pool   = (float*)(ws + off); off += 2048;
    float* cnt    = (float*)(ws + off); off += 2048;

    const int NB = (NN + 255) / 256;   // 391 scan blocks

    // --- CSR build + degree norm ---
    hipMemsetAsync(deg, 0, NN * sizeof(int), stream);
    hipMemsetAsync(pool, 0, 4096, stream);                   // pool + cnt
    k_hist<<<(E + 255) / 256, 256, 0, stream>>>(dst, deg, E);
    k_scan_block<<<NB, 256, 0, stream>>>(deg, rowptr, bsum, NN);
    k_scan_top<<<1, 512, 0, stream>>>(bsum, NB);
    k_scan_fin<<<NB, 256, 0, stream>>>(rowptr, bsum, deg, cursor, dinv, NN, E);
    k_fill<<<(E + 255) / 256, 256, 0, stream>>>(src, dst, cursor, col, E);
    k_sortrows<<<(NN + 3) / 4, 256, 0, stream>>>(rowptr, col, NN);

    // --- layer 1 ---
    gemm128h<<<NN / 32, 256, 0, stream>>>(x, W1, dinv, tS);
    k_gather1<<<(NN + 3) / 4, 256, 0, stream>>>(tS, rowptr, col, dinv, b1, h1, NN);

    // --- layer 2 ---
    gemm128h<<<NN / 32, 256, 0, stream>>>(h1, W2, dinv, tS);
    k_gather2<<<(NN + 3) / 4, 256, 0, stream>>>(tS, rowptr, col, dinv, b2, Wp,
                                                batch, pool, cnt, NN);

    // --- head ---
    final_out_kernel<<<(NG + 255) / 256, 256, 0, stream>>>(pool, cnt, bp, out, NG);
}

// Round 7
// 704.552 us; speedup vs baseline: 1.0596x; 1.0596x over previous
//
#include <hip/hip_runtime.h>
#include <hip/hip_bf16.h>

// Problem constants (match reference)
#define NN 100000
#define NG 512
#define H  128

typedef _Float16 half8 __attribute__((ext_vector_type(8)));
typedef _Float16 half4v __attribute__((ext_vector_type(4)));
typedef float f32x4 __attribute__((ext_vector_type(4)));

// ---------------------------------------------------------------------------
// CSR build: histogram of dst
__global__ __launch_bounds__(256) void k_hist(const int* __restrict__ dst,
                                              int* __restrict__ deg, int E) {
    int e = blockIdx.x * 256 + threadIdx.x;
    if (e < E) atomicAdd(&deg[dst[e]], 1);
}

// per-block exclusive scan (256 elems), partial sums to bsum
__global__ __launch_bounds__(256) void k_scan_block(const int* __restrict__ deg,
                                                    int* __restrict__ rowptr,
                                                    int* __restrict__ bsum, int n) {
    __shared__ int s[256];
    int tid = threadIdx.x;
    int i = blockIdx.x * 256 + tid;
    int v = (i < n) ? deg[i] : 0;
    s[tid] = v;
    __syncthreads();
    #pragma unroll
    for (int off = 1; off < 256; off <<= 1) {
        int t = (tid >= off) ? s[tid - off] : 0;
        __syncthreads();
        s[tid] += t;
        __syncthreads();
    }
    if (i < n) rowptr[i] = s[tid] - v;            // exclusive within block
    if (tid == 255) bsum[blockIdx.x] = s[255];    // block total
}

// scan of block sums (NB <= 512), single block
__global__ __launch_bounds__(512) void k_scan_top(int* __restrict__ bsum, int nb) {
    __shared__ int s[512];
    int tid = threadIdx.x;
    int v = (tid < nb) ? bsum[tid] : 0;
    s[tid] = v;
    __syncthreads();
    #pragma unroll
    for (int off = 1; off < 512; off <<= 1) {
        int t = (tid >= off) ? s[tid - off] : 0;
        __syncthreads();
        s[tid] += t;
        __syncthreads();
    }
    if (tid < nb) bsum[tid] = s[tid] - v;         // exclusive
}

// finalize: rowptr += block offset; cursor = rowptr; dinv = rsqrt(deg+1)
__global__ __launch_bounds__(256) void k_scan_fin(int* __restrict__ rowptr,
                                                  const int* __restrict__ bsum,
                                                  const int* __restrict__ deg,
                                                  int* __restrict__ cursor,
                                                  float* __restrict__ dinv,
                                                  int n, int E) {
    int i = blockIdx.x * 256 + threadIdx.x;
    if (i >= n) return;
    int r = rowptr[i] + bsum[i >> 8];
    rowptr[i] = r;
    cursor[i] = r;
    dinv[i] = rsqrtf((float)deg[i] + 1.0f);       // +1 self-loop; always > 0
    if (i == 0) rowptr[n] = E;
}

// fill CSR column array
__global__ __launch_bounds__(256) void k_fill(const int* __restrict__ src,
                                              const int* __restrict__ dst,
                                              int* __restrict__ cursor,
                                              int* __restrict__ col, int E) {
    int e = blockIdx.x * 256 + threadIdx.x;
    if (e >= E) return;
    int d = dst[e];
    int pos = atomicAdd(&cursor[d], 1);
    col[pos] = src[e];
}

// ---------------------------------------------------------------------------
// Sort each CSR row ascending (locality only — correctness is order-free).
__global__ __launch_bounds__(256) void k_sortrows(const int* __restrict__ rowptr,
                                                  int* __restrict__ col, int n) {
    int node = blockIdx.x * 4 + (threadIdx.x >> 6);
    int lane = threadIdx.x & 63;
    if (node >= n) return;
    int e0 = rowptr[node], end = rowptr[node + 1];
    int deg = end - e0;
    if (deg <= 1 || deg > 64) return;             // wave-uniform branch
    int v = (lane < deg) ? col[e0 + lane] : 0x7fffffff;
    #pragma unroll
    for (int k = 2; k <= 64; k <<= 1) {
        #pragma unroll
        for (int j = k >> 1; j > 0; j >>= 1) {
            int p = __shfl_xor(v, j);
            bool up = ((lane & k) == 0);
            bool keepmin = (((lane & j) == 0) == up);
            v = keepmin ? min(v, p) : max(v, p);
        }
    }
    if (lane < deg) col[e0 + lane] = v;
}

// ---------------------------------------------------------------------------
// fp32 -> fp16 conversion (for x)
__global__ __launch_bounds__(256) void k_cvt_h(const float* __restrict__ in,
                                               _Float16* __restrict__ out, int n4) {
    int i = blockIdx.x * 256 + threadIdx.x;
    if (i >= n4) return;
    float4 v = ((const float4*)in)[i];
    half4v h;
    h[0] = (_Float16)v.x;
    h[1] = (_Float16)v.y;
    h[2] = (_Float16)v.z;
    h[3] = (_Float16)v.w;
    ((half4v*)out)[i] = h;
}

// ---------------------------------------------------------------------------
// MFMA GEMM: C_h[n x 128] (fp16) = (A_h[n x 128] @ W[128 x 128]) * scale[row].
// 64 rows/block, 4 waves (wave w -> rows w*16..+15), 16x16x32 f16 MFMA.
// A staged to LDS fp16 (row pad +8 halves); W transposed to Wt[n][k] so
// B-fragments (fixed n, 8 consecutive k per lane) are contiguous b128 reads.
// Verified layouts (m89/m120): A[m=lane&15][k=(lane>>4)*8+j];
// B[n=lane&15][k=(lane>>4)*8+j]; C col=lane&15, row=(lane>>4)*4+reg.
#define LDA 136   // 128 + 8 fp16 pad
__global__ __launch_bounds__(256) void gemm_mfma(const _Float16* __restrict__ A,
                                                 const float* __restrict__ W,
                                                 const float* __restrict__ scale,
                                                 _Float16* __restrict__ C, int n) {
    __shared__ _Float16 As[64 * LDA];
    __shared__ _Float16 Wt[128 * LDA];
    const int tid = threadIdx.x;
    const int row0 = blockIdx.x * 64;

    // stage A: 64 rows x 16 half8 = 1024 half8, 4 per thread
    #pragma unroll
    for (int i = 0; i < 4; ++i) {
        int f = i * 256 + tid;
        int r = f >> 4, c8 = f & 15;
        int gr = row0 + r;
        half8 v;
        #pragma unroll
        for (int j = 0; j < 8; ++j) v[j] = (_Float16)0.0f;
        if (gr < n) v = ((const half8*)(A + (size_t)gr * H))[c8];
        *((half8*)(As + r * LDA + c8 * 8)) = v;
    }
    // stage W transposed: 128 rows x 32 float4 = 4096 float4, 16 per thread
    #pragma unroll
    for (int i = 0; i < 16; ++i) {
        int f = i * 256 + tid;
        int k = f >> 5, c4 = f & 31;
        float4 v = ((const float4*)(W + (size_t)k * H))[c4];
        Wt[(c4 * 4 + 0) * LDA + k] = (_Float16)v.x;
        Wt[(c4 * 4 + 1) * LDA + k] = (_Float16)v.y;
        Wt[(c4 * 4 + 2) * LDA + k] = (_Float16)v.z;
        Wt[(c4 * 4 + 3) * LDA + k] = (_Float16)v.w;
    }
    __syncthreads();

    const int w = tid >> 6;
    const int lane = tid & 63;
    const int l16 = lane & 15, quad = lane >> 4;
    f32x4 acc[8] = {};
    const _Float16* aBase = As + (w * 16 + l16) * LDA + quad * 8;
    const _Float16* bBase = Wt + l16 * LDA + quad * 8;
    #pragma unroll
    for (int kk = 0; kk < 4; ++kk) {
        half8 af = *((const half8*)(aBase + kk * 32));
        #pragma unroll
        for (int nt = 0; nt < 8; ++nt) {
            half8 bf = *((const half8*)(bBase + nt * 16 * LDA + kk * 32));
            acc[nt] = __builtin_amdgcn_mfma_f32_16x16x32_f16(af, bf, acc[nt], 0, 0, 0);
        }
    }
    // epilogue: C[row=quad*4+r][col=nt*16+l16]
    #pragma unroll
    for (int r = 0; r < 4; ++r) {
        int R = row0 + w * 16 + quad * 4 + r;
        if (R < n) {
            float sc = scale[R];
            _Float16* crow = C + (size_t)R * H + l16;
            #pragma unroll
            for (int nt = 0; nt < 8; ++nt)
                crow[nt * 16] = (_Float16)(acc[nt][r] * sc);
        }
    }
}

// ---------------------------------------------------------------------------
// Gather core, fp16 rows (256B). One wave per node; quarter-wave per edge slot.
__device__ __forceinline__ void gather_rows_h(const half8* __restrict__ t8,
                                              const int* __restrict__ col,
                                              int node, int e0, int end,
                                              float acc[8]) {
    const int lane = threadIdx.x & 63;
    const int q = lane >> 4;
    const int l16 = lane & 15;
    float a0[8] = {}, a1[8] = {};
    if (q == 0) {                                   // self-loop row
        half8 v = t8[(size_t)node * 16 + l16];
        #pragma unroll
        for (int i = 0; i < 8; ++i) a0[i] = (float)v[i];
    }
    for (int base = e0; base < end; base += 64) {
        int ce = base + lane;
        int cidx = (ce < end) ? col[ce] : 0;
        int m = min(64, end - base);
        int nf = m >> 2;                            // full groups of 4 edges
        int g = 0;
        for (; g + 2 <= nf; g += 2) {
            int s0 = __shfl(cidx, 4 * g + q);
            int s1 = __shfl(cidx, 4 * g + 4 + q);
            half8 v0 = t8[(size_t)s0 * 16 + l16];
            half8 v1 = t8[(size_t)s1 * 16 + l16];
            #pragma unroll
            for (int i = 0; i < 8; ++i) {
                a0[i] += (float)v0[i];
                a1[i] += (float)v1[i];
            }
        }
        if (g < nf) {
            int s0 = __shfl(cidx, 4 * g + q);
            half8 v0 = t8[(size_t)s0 * 16 + l16];
            #pragma unroll
            for (int i = 0; i < 8; ++i) a0[i] += (float)v0[i];
        }
        int tail = m & 3;
        if (tail) {
            int s = __shfl(cidx, 4 * nf + q);       // all lanes active here
            if (q < tail) {
                half8 v = t8[(size_t)s * 16 + l16];
                #pragma unroll
                for (int i = 0; i < 8; ++i) a0[i] += (float)v[i];
            }
        }
    }
    #pragma unroll
    for (int i = 0; i < 8; ++i) {
        float t = a0[i] + a1[i];
        t += __shfl_xor(t, 16);
        t += __shfl_xor(t, 32);
        acc[i] = t;
    }
}

// gather layer 1: out[n] (fp16) = relu(dinv[n]*(tS[n] + sum in-edges) + b)
__global__ __launch_bounds__(256) void k_gather1(const _Float16* __restrict__ tS,
                                                 const int* __restrict__ rowptr,
                                                 const int* __restrict__ col,
                                                 const float* __restrict__ dinv,
                                                 const float* __restrict__ b,
                                                 _Float16* __restrict__ out, int n) {
    int node = blockIdx.x * 4 + (threadIdx.x >> 6);
    int lane = threadIdx.x & 63;
    int q = lane >> 4, l16 = lane & 15;
    if (node >= n) return;
    int e0 = rowptr[node], end = rowptr[node + 1];
    float acc[8];
    gather_rows_h((const half8*)tS, col, node, e0, end, acc);
    if (q == 0) {
        float dn = dinv[node];
        const float4* b4 = (const float4*)b;
        float4 bb0 = b4[2 * l16], bb1 = b4[2 * l16 + 1];
        half8 hv;
        hv[0] = (_Float16)fmaxf(dn * acc[0] + bb0.x, 0.0f);
        hv[1] = (_Float16)fmaxf(dn * acc[1] + bb0.y, 0.0f);
        hv[2] = (_Float16)fmaxf(dn * acc[2] + bb0.z, 0.0f);
        hv[3] = (_Float16)fmaxf(dn * acc[3] + bb0.w, 0.0f);
        hv[4] = (_Float16)fmaxf(dn * acc[4] + bb1.x, 0.0f);
        hv[5] = (_Float16)fmaxf(dn * acc[5] + bb1.y, 0.0f);
        hv[6] = (_Float16)fmaxf(dn * acc[6] + bb1.z, 0.0f);
        hv[7] = (_Float16)fmaxf(dn * acc[7] + bb1.w, 0.0f);
        ((half8*)out)[(size_t)node * 16 + l16] = hv;
    }
}

// gather layer 2 fused with pool head: v = relu(...); pool[batch[n]] += dot(v, Wp)
__global__ __launch_bounds__(256) void k_gather2(const _Float16* __restrict__ tS,
                                                 const int* __restrict__ rowptr,
                                                 const int* __restrict__ col,
                                                 const float* __restrict__ dinv,
                                                 const float* __restrict__ b,
                                                 const float* __restrict__ Wp,
                                                 const int* __restrict__ batch,
                                                 float* __restrict__ pool,
                                                 float* __restrict__ cnt, int n) {
    int node = blockIdx.x * 4 + (threadIdx.x >> 6);
    int lane = threadIdx.x & 63;
    int l16 = lane & 15;
    if (node >= n) return;
    int e0 = rowptr[node], end = rowptr[node + 1];
    float acc[8];
    gather_rows_h((const half8*)tS, col, node, e0, end, acc);
    float dn = dinv[node];
    const float4* b4 = (const float4*)b;
    const float4* w4 = (const float4*)Wp;
    float4 bb0 = b4[2 * l16], bb1 = b4[2 * l16 + 1];
    float4 wp0 = w4[2 * l16], wp1 = w4[2 * l16 + 1];
    float s = fmaxf(dn * acc[0] + bb0.x, 0.0f) * wp0.x +
              fmaxf(dn * acc[1] + bb0.y, 0.0f) * wp0.y +
              fmaxf(dn * acc[2] + bb0.z, 0.0f) * wp0.z +
              fmaxf(dn * acc[3] + bb0.w, 0.0f) * wp0.w +
              fmaxf(dn * acc[4] + bb1.x, 0.0f) * wp1.x +
              fmaxf(dn * acc[5] + bb1.y, 0.0f) * wp1.y +
              fmaxf(dn * acc[6] + bb1.z, 0.0f) * wp1.z +
              fmaxf(dn * acc[7] + bb1.w, 0.0f) * wp1.w;
    s += __shfl_xor(s, 1);
    s += __shfl_xor(s, 2);
    s += __shfl_xor(s, 4);
    s += __shfl_xor(s, 8);
    if (lane == 0) {
        int g = batch[node];
        atomicAdd(&pool[g], s);
        atomicAdd(&cnt[g], 1.0f);
    }
}

// ---------------------------------------------------------------------------
__global__ __launch_bounds__(256) void final_out_kernel(const float* __restrict__ pool,
                                                        const float* __restrict__ cnt,
                                                        const float* __restrict__ bp,
                                                        float* __restrict__ out, int g) {
    int i = blockIdx.x * 256 + threadIdx.x;
    if (i < g) out[i] = pool[i] / fmaxf(cnt[i], 1.0f) + bp[0];
}

// ---------------------------------------------------------------------------
extern "C" void kernel_launch(void* const* d_in, const int* in_sizes, int n_in,
                              void* d_out, int out_size, void* d_ws, size_t ws_size,
                              hipStream_t stream) {
    const float* x     = (const float*)d_in[0];
    const int*   ei    = (const int*)d_in[1];   // [2, E]: src = ei[0:E], dst = ei[E:2E]
    const int*   batch = (const int*)d_in[2];
    const float* W1    = (const float*)d_in[3];
    const float* b1    = (const float*)d_in[4];
    const float* W2    = (const float*)d_in[5];
    const float* b2    = (const float*)d_in[6];
    const float* Wp    = (const float*)d_in[7];
    const float* bp    = (const float*)d_in[8];
    float* out = (float*)d_out;

    const int E = in_sizes[1] / 2;   // 1,600,000
    const int* src = ei;
    const int* dst = ei + E;

    // workspace layout (aligned chunks)
    const size_t BUFH = (size_t)NN * H * sizeof(_Float16);   // 25.6 MB
    const size_t NI  = 401408;                                // >= (NN+1)*4, 4KB-mult
    char* ws = (char*)d_ws;
    size_t off = 0;
    _Float16* tS  = (_Float16*)(ws + off); off += BUFH;      // GEMM outputs (fp16)
    _Float16* h1  = (_Float16*)(ws + off); off += BUFH;      // layer-1 acts (fp16)
    _Float16* xh  = (_Float16*)(ws + off); off += BUFH;      // x cast to fp16
    int*   deg    = (int*)  (ws + off); off += NI;
    int*   rowptr = (int*)  (ws + off); off += NI;
    int*   cursor = (int*)  (ws + off); off += NI;
    float* dinv   = (float*)(ws + off); off += NI;
    int*   col    = (int*)  (ws + off); off += ((size_t)E * 4 + 4095) / 4096 * 4096;
    int*   bsum   = (int*)  (ws + off); off += 4096;
    float* pool   = (float*)(ws + off); off += 2048;
    float* cnt    = (float*)(ws + off); off += 2048;

    const int NB = (NN + 255) / 256;   // 391 scan blocks

    // --- CSR build + degree norm ---
    hipMemsetAsync(deg, 0, NN * sizeof(int), stream);
    hipMemsetAsync(pool, 0, 4096, stream);                   // pool + cnt
    k_hist<<<(E + 255) / 256, 256, 0, stream>>>(dst, deg, E);
    k_scan_block<<<NB, 256, 0, stream>>>(deg, rowptr, bsum, NN);
    k_scan_top<<<1, 512, 0, stream>>>(bsum, NB);
    k_scan_fin<<<NB, 256, 0, stream>>>(rowptr, bsum, deg, cursor, dinv, NN, E);
    k_fill<<<(E + 255) / 256, 256, 0, stream>>>(src, dst, cursor, col, E);
    k_sortrows<<<(NN + 3) / 4, 256, 0, stream>>>(rowptr, col, NN);

    // --- x -> fp16 ---
    k_cvt_h<<<(NN * 32 + 255) / 256, 256, 0, stream>>>(x, xh, NN * 32);

    // --- layer 1 ---
    gemm_mfma<<<(NN + 63) / 64, 256, 0, stream>>>(xh, W1, dinv, tS, NN);
    k_gather1<<<(NN + 3) / 4, 256, 0, stream>>>(tS, rowptr, col, dinv, b1, h1, NN);

    // --- layer 2 ---
    gemm_mfma<<<(NN + 63) / 64, 256, 0, stream>>>(h1, W2, dinv, tS, NN);
    k_gather2<<<(NN + 3) / 4, 256, 0, stream>>>(tS, rowptr, col, dinv, b2, Wp,
                                                batch, pool, cnt, NN);

    // --- head ---
    final_out_kernel<<<(NG + 255) / 256, 256, 0, stream>>>(pool, cnt, bp, out, NG);
}